// Round 2
// 1331.856 us; speedup vs baseline: 1.2434x; 1.2434x over previous
//
#include <hip/hip_runtime.h>
#include <hip/hip_bf16.h>
#include <cstdint>
#include <cstddef>

// Problem: out[M,N] = x[M,K] @ W[N,K]^T + bias[N], W = (q - zp)*scale
// M = B*S = 8192, K = 4096, N = 11008. fp32 in/out, q int32.
#define M_DIM 8192
#define N_DIM 11008
#define K_DIM 4096

typedef __bf16 bf16x8 __attribute__((ext_vector_type(8)));
typedef float  f32x4  __attribute__((ext_vector_type(4)));

__device__ inline __bf16 to_bf16(float f) {
    __hip_bfloat16 h = __float2bfloat16(f);
    return *reinterpret_cast<__bf16*>(&h);
}

union Pack4 { __bf16 h[4]; uint2 u; };

// ---------------- conversion kernels (bf16 fast path) ----------------

__global__ void cvt_x_kernel(const float* __restrict__ x, __bf16* __restrict__ out) {
    int i = blockIdx.x * blockDim.x + threadIdx.x;   // one float4 per thread
    float4 v = *reinterpret_cast<const float4*>(x + (size_t)i * 4);
    Pack4 p;
    p.h[0] = to_bf16(v.x); p.h[1] = to_bf16(v.y);
    p.h[2] = to_bf16(v.z); p.h[3] = to_bf16(v.w);
    *reinterpret_cast<uint2*>(out + (size_t)i * 4) = p.u;
}

__global__ void cvt_w_kernel(const int* __restrict__ q,
                             const float* __restrict__ scale_p,
                             const float* __restrict__ zp_p,
                             __bf16* __restrict__ out) {
    const float scale = *scale_p;
    const float nzs   = -(*zp_p) * scale;   // (q - zp)*s = q*s + (-zp*s)
    int i = blockIdx.x * blockDim.x + threadIdx.x;
    int4 v = *reinterpret_cast<const int4*>(q + (size_t)i * 4);
    Pack4 p;
    p.h[0] = to_bf16((float)v.x * scale + nzs);
    p.h[1] = to_bf16((float)v.y * scale + nzs);
    p.h[2] = to_bf16((float)v.z * scale + nzs);
    p.h[3] = to_bf16((float)v.w * scale + nzs);
    *reinterpret_cast<uint2*>(out + (size_t)i * 4) = p.u;
}

__device__ inline void async_load16(const void* gsrc, void* ldst) {
    __builtin_amdgcn_global_load_lds(
        (const __attribute__((address_space(1))) unsigned int*)gsrc,
        (__attribute__((address_space(3))) unsigned int*)ldst, 16, 0, 0);
}

// ---------------- fast path: 256x256x64 8-phase bf16 GEMM ----------------
// Schedule (per K-tile t, 4 phases; 2 K-tiles per "8-phase iter"):
//   phase q: ds_read A-quadrant q (rows q*64..q*64+63, XOR-swizzled)
//            [+ all 8 B frags in phase 0]
//            stage one half-tile:   p0: A-h1(t+1) | p1: B-h0(t+2) | p2: B-h1(t+2) | p3: A-h0(t+2)
//            s_barrier; lgkmcnt(0); setprio(1); 16 MFMA; setprio(0); s_barrier
//   boundary (after p3): s_waitcnt vmcnt(6)  -- 3 half-tiles (t+2's) stay in flight
// Region-reuse proof: A-h0(buf) dead after p1, A-h1 after p3, B after p0;
// each overwrite is issued >=1 phase after last read + separated by barriers.
// LDS swizzle (T2, both-sides): phys_byte = row*128 + (colbyte ^ ((row&7)<<4));
// global_load_lds writes linearly, so the SOURCE k-col is pre-swizzled:
// lane i of a 1KB chunk fetches col 8*((i&7)^(i>>3)) of row c*8+(i>>3).

constexpr int BM = 256, BN = 256, BK = 64;
constexpr int NT  = K_DIM / BK;            // 64 K-tiles
constexpr int NBN = N_DIM / BN;            // 43
constexpr int NWG = (M_DIM / BM) * NBN;    // 1376 (== 0 mod 8)

__global__ __launch_bounds__(512, 2)
void gemm_bf16_kernel(const __bf16* __restrict__ A, const __bf16* __restrict__ B,
                      const float* __restrict__ bias, float* __restrict__ C) {
    __shared__ __align__(16) __bf16 As[2][BM * BK];   // 2 x 32 KB
    __shared__ __align__(16) __bf16 Bs[2][BN * BK];   // 2 x 32 KB  (128 KB total)

    const int tid  = threadIdx.x;
    const int lane = tid & 63;
    const int wave = tid >> 6;       // 0..7
    const int wr   = wave >> 2;      // 0..1 (M)
    const int wc   = wave & 3;       // 0..3 (N)

    // T1: bijective XCD-contiguous remap (NWG % 8 == 0)
    int wg = (int)blockIdx.x;
    wg = (wg & 7) * (NWG >> 3) + (wg >> 3);
    const int bm = (wg / NBN) * BM;
    const int bn = (wg % NBN) * BN;

    // ---- staging geometry (inverse-swizzled global source, linear LDS dest) ----
    const int rc   = lane >> 3;                  // row within 8-row chunk
    const int scol = 8 * ((lane & 7) ^ rc);      // pre-swizzled k-col (bf16 elems)
    const int c0   = wave * 2;                   // this wave's 2 chunks per half-tile

#define STAGE_A(bufx, h, t) do {                                                      \
    _Pragma("unroll") for (int l = 0; l < 2; ++l) {                                   \
        const int c = c0 + l;                                                         \
        async_load16(A + (size_t)(bm + (h)*128 + c*8 + rc) * K_DIM + (t)*BK + scol,   \
                     (char*)As[bufx] + (h)*16384 + c*1024 + lane*16);                 \
    } } while (0)
#define STAGE_B(bufx, h, t) do {                                                      \
    _Pragma("unroll") for (int l = 0; l < 2; ++l) {                                   \
        const int c = c0 + l;                                                         \
        async_load16(B + (size_t)(bn + (h)*128 + c*8 + rc) * K_DIM + (t)*BK + scol,   \
                     (char*)Bs[bufx] + (h)*16384 + c*1024 + lane*16);                 \
    } } while (0)

    // ---- fragment-read geometry (swizzled ds_read_b128) ----
    const int lrow = lane & 15;
    const int swz  = (lane & 7) << 4;
    const int csw0 = (((lane >> 4) * 16)      ) ^ swz;   // ks=0 col-bytes, swizzled
    const int csw1 = (((lane >> 4) * 16) + 64 ) ^ swz;   // ks=1
    const int a_base = (wr * 32 + lrow) * 128;           // M interleaved at 32 rows
    const int b_base = (wc * 64 + lrow) * 128;

    f32x4 acc[8][4] = {};

    // ---- prologue: tile0 fully + tile1's first 3 half-tiles ----
    STAGE_B(0, 0, 0); STAGE_B(0, 1, 0); STAGE_A(0, 0, 0); STAGE_A(0, 1, 0);
    STAGE_B(1, 0, 1); STAGE_B(1, 1, 1); STAGE_A(1, 0, 1);
    asm volatile("s_waitcnt vmcnt(6)" ::: "memory");   // tile0 complete
    __builtin_amdgcn_s_barrier();

#define PHASE_Q(q, STAGE_STMT, TAIL) do {                                                         \
    bf16x8 a00 = *reinterpret_cast<const bf16x8*>(asp + a_base + (q)*8192 + csw0);                \
    bf16x8 a01 = *reinterpret_cast<const bf16x8*>(asp + a_base + (q)*8192 + csw1);                \
    bf16x8 a10 = *reinterpret_cast<const bf16x8*>(asp + a_base + (q)*8192 + 2048 + csw0);         \
    bf16x8 a11 = *reinterpret_cast<const bf16x8*>(asp + a_base + (q)*8192 + 2048 + csw1);         \
    STAGE_STMT;                                                                                   \
    __builtin_amdgcn_s_barrier();                                                                 \
    asm volatile("s_waitcnt lgkmcnt(0)" ::: "memory");                                            \
    __builtin_amdgcn_s_setprio(1);                                                                \
    _Pragma("unroll") for (int j = 0; j < 4; ++j) {                                               \
        acc[2*(q)  ][j] = __builtin_amdgcn_mfma_f32_16x16x32_bf16(a00, bfr[j][0], acc[2*(q)  ][j], 0,0,0); \
        acc[2*(q)  ][j] = __builtin_amdgcn_mfma_f32_16x16x32_bf16(a01, bfr[j][1], acc[2*(q)  ][j], 0,0,0); \
        acc[2*(q)+1][j] = __builtin_amdgcn_mfma_f32_16x16x32_bf16(a10, bfr[j][0], acc[2*(q)+1][j], 0,0,0); \
        acc[2*(q)+1][j] = __builtin_amdgcn_mfma_f32_16x16x32_bf16(a11, bfr[j][1], acc[2*(q)+1][j], 0,0,0); \
    }                                                                                             \
    __builtin_amdgcn_s_setprio(0);                                                                \
    TAIL;                                                                                         \
} while (0)

    for (int t = 0; t < NT; ++t) {
        const int buf = t & 1;
        const int nb  = buf ^ 1;
        const char* asp = (const char*)As[buf];
        const char* bsp = (const char*)Bs[buf];

        bf16x8 bfr[4][2];   // all B frags for this K-tile (read once, phase 0)
#pragma unroll
        for (int j = 0; j < 4; ++j) {
            bfr[j][0] = *reinterpret_cast<const bf16x8*>(bsp + b_base + j*2048 + csw0);
            bfr[j][1] = *reinterpret_cast<const bf16x8*>(bsp + b_base + j*2048 + csw1);
        }

        PHASE_Q(0, if (t + 1 < NT) STAGE_A(nb, 1, t + 1), __builtin_amdgcn_s_barrier());
        PHASE_Q(1, if (t + 2 < NT) STAGE_B(buf, 0, t + 2), __builtin_amdgcn_s_barrier());
        PHASE_Q(2, if (t + 2 < NT) STAGE_B(buf, 1, t + 2), __builtin_amdgcn_s_barrier());
        PHASE_Q(3, if (t + 2 < NT) STAGE_A(buf, 0, t + 2),
                { if (t < NT - 2)       { asm volatile("s_waitcnt vmcnt(6)" ::: "memory");
                                          __builtin_amdgcn_s_barrier(); }
                  else if (t == NT - 2) { asm volatile("s_waitcnt vmcnt(0)" ::: "memory");
                                          __builtin_amdgcn_s_barrier(); } });
    }

    // ---- epilogue: C/D layout col=lane&15, row=(lane>>4)*4+reg ----
    const int col16 = lane & 15;
    const int rq    = (lane >> 4) * 4;
#pragma unroll
    for (int j = 0; j < 4; ++j) {
        const int n  = bn + wc * 64 + j * 16 + col16;
        const float bj = bias[n];
#pragma unroll
        for (int i = 0; i < 8; ++i) {
            const int row0 = bm + (i >> 1) * 64 + wr * 32 + (i & 1) * 16 + rq;
            size_t base = (size_t)row0 * N_DIM + n;
#pragma unroll
            for (int r = 0; r < 4; ++r)
                C[base + (size_t)r * N_DIM] = acc[i][j][r] + bj;
        }
    }
#undef PHASE_Q
#undef STAGE_A
#undef STAGE_B
}

// ---------------- fallback: fused dequant GEMM (no workspace needed) ----------------

constexpr int FBM = 128, FBN = 128, FBK = 64;

__device__ inline void mma_tile_f(const __bf16* As, const __bf16* Bs,
                                  f32x4 acc[4][4], int lane, int wm, int wn) {
    const int mrow = lane & 15;
#pragma unroll
    for (int ks = 0; ks < 2; ++ks) {
        const int kq = ks * 32 + (lane >> 4) * 8;
        bf16x8 a[4], b[4];
#pragma unroll
        for (int i = 0; i < 4; ++i) {
            a[i] = *reinterpret_cast<const bf16x8*>(As + (wm + i * 16 + mrow) * FBK + kq);
            b[i] = *reinterpret_cast<const bf16x8*>(Bs + (wn + i * 16 + mrow) * FBK + kq);
        }
#pragma unroll
        for (int i = 0; i < 4; ++i)
#pragma unroll
            for (int j = 0; j < 4; ++j)
                acc[i][j] = __builtin_amdgcn_mfma_f32_16x16x32_bf16(a[i], b[j], acc[i][j], 0, 0, 0);
    }
}

__global__ __launch_bounds__(256)
void gemm_fused_kernel(const float* __restrict__ A, const int* __restrict__ Q,
                       const float* __restrict__ scale_p, const float* __restrict__ zp_p,
                       const float* __restrict__ bias, float* __restrict__ C) {
    __shared__ __align__(16) __bf16 As[FBM * FBK];
    __shared__ __align__(16) __bf16 Bs[FBN * FBK];

    const float scale = *scale_p;
    const float nzs   = -(*zp_p) * scale;

    const int tid  = threadIdx.x;
    const int lane = tid & 63;
    const int wave = tid >> 6;
    const int bm = blockIdx.y * FBM;
    const int bn = blockIdx.x * FBN;
    const int wm = (wave >> 1) * 64;
    const int wn = (wave & 1) * 64;

    f32x4 acc[4][4] = {};

    for (int k0 = 0; k0 < K_DIM; k0 += FBK) {
        __syncthreads();
#pragma unroll
        for (int j = 0; j < 8; ++j) {
            const int e   = j * 1024 + tid * 4;
            const int row = e >> 6;
            const int col = e & 63;
            float4 v = *reinterpret_cast<const float4*>(A + (size_t)(bm + row) * K_DIM + k0 + col);
            Pack4 p;
            p.h[0] = to_bf16(v.x); p.h[1] = to_bf16(v.y);
            p.h[2] = to_bf16(v.z); p.h[3] = to_bf16(v.w);
            *reinterpret_cast<uint2*>(As + e) = p.u;

            int4 qv = *reinterpret_cast<const int4*>(Q + (size_t)(bn + row) * K_DIM + k0 + col);
            Pack4 pq;
            pq.h[0] = to_bf16((float)qv.x * scale + nzs);
            pq.h[1] = to_bf16((float)qv.y * scale + nzs);
            pq.h[2] = to_bf16((float)qv.z * scale + nzs);
            pq.h[3] = to_bf16((float)qv.w * scale + nzs);
            *reinterpret_cast<uint2*>(Bs + e) = pq.u;
        }
        __syncthreads();
        mma_tile_f(As, Bs, acc, lane, wm, wn);
    }

    const int col = lane & 15;
    const int rq  = (lane >> 4) * 4;
#pragma unroll
    for (int j = 0; j < 4; ++j) {
        const int n  = bn + wn + j * 16 + col;
        const float bj = bias[n];
#pragma unroll
        for (int i = 0; i < 4; ++i) {
            size_t base = (size_t)(bm + wm + i * 16 + rq) * N_DIM + n;
#pragma unroll
            for (int r = 0; r < 4; ++r)
                C[base + (size_t)r * N_DIM] = acc[i][j][r] + bj;
        }
    }
}

// ---------------- launch ----------------

extern "C" void kernel_launch(void* const* d_in, const int* in_sizes, int n_in,
                              void* d_out, int out_size, void* d_ws, size_t ws_size,
                              hipStream_t stream) {
    const float* x     = (const float*)d_in[0];
    const int*   qw    = (const int*)d_in[1];
    const float* scale = (const float*)d_in[2];
    const float* zp    = (const float*)d_in[3];
    const float* bias  = (const float*)d_in[4];
    float* out = (float*)d_out;

    const size_t needA = (size_t)M_DIM * K_DIM * sizeof(__bf16);   // 67.1 MB
    const size_t needB = (size_t)N_DIM * K_DIM * sizeof(__bf16);   // 90.2 MB

    if (ws_size >= needA + needB) {
        __bf16* Abf = (__bf16*)d_ws;
        __bf16* Bbf = (__bf16*)((char*)d_ws + needA);
        cvt_x_kernel<<<(M_DIM * (size_t)K_DIM / 4) / 256, 256, 0, stream>>>(x, Abf);
        cvt_w_kernel<<<(N_DIM * (size_t)K_DIM / 4) / 256, 256, 0, stream>>>(qw, scale, zp, Bbf);
        gemm_bf16_kernel<<<dim3(NWG), 512, 0, stream>>>(Abf, Bbf, bias, out);
    } else {
        gemm_fused_kernel<<<dim3(N_DIM / FBN, M_DIM / FBM), 256, 0, stream>>>(x, qw, scale, zp, bias, out);
    }
}

// Round 3
// 1235.930 us; speedup vs baseline: 1.3399x; 1.0776x over previous
//
#include <hip/hip_runtime.h>
#include <hip/hip_bf16.h>
#include <cstdint>
#include <cstddef>

// Problem: out[M,N] = x[M,K] @ W[N,K]^T + bias[N], W = (q - zp)*scale
// M = B*S = 8192, K = 4096, N = 11008. fp32 in/out, q int32.
#define M_DIM 8192
#define N_DIM 11008
#define K_DIM 4096

typedef __bf16 bf16x8 __attribute__((ext_vector_type(8)));
typedef float  f32x4  __attribute__((ext_vector_type(4)));
typedef float  f32x4v __attribute__((ext_vector_type(4)));
typedef int    i32x4v __attribute__((ext_vector_type(4)));

__device__ inline __bf16 to_bf16(float f) {
    __hip_bfloat16 h = __float2bfloat16(f);
    return *reinterpret_cast<__bf16*>(&h);
}

union Pack4 { __bf16 h[4]; uint2 u; };
union Pack8 { __bf16 h[8]; uint4 u; };

// ---------------- conversion kernels (bf16 fast path) ----------------
// 8 elems/thread: 16B/lane stores (coalescing sweet spot, G13).
// NT loads: inputs are read-once; keep LLC clean for the bf16 A/B panels
// the GEMM will re-read. Outputs use NORMAL stores (want LLC residency).

__global__ void cvt_x_kernel(const float* __restrict__ x, __bf16* __restrict__ out) {
    size_t i = (size_t)(blockIdx.x * (size_t)blockDim.x + threadIdx.x) * 8;
    f32x4v v0 = __builtin_nontemporal_load(reinterpret_cast<const f32x4v*>(x + i));
    f32x4v v1 = __builtin_nontemporal_load(reinterpret_cast<const f32x4v*>(x + i + 4));
    Pack8 p;
#pragma unroll
    for (int j = 0; j < 4; ++j) { p.h[j] = to_bf16(v0[j]); p.h[4 + j] = to_bf16(v1[j]); }
    *reinterpret_cast<uint4*>(out + i) = p.u;
}

__global__ void cvt_w_kernel(const int* __restrict__ q,
                             const float* __restrict__ scale_p,
                             const float* __restrict__ zp_p,
                             __bf16* __restrict__ out) {
    const float scale = *scale_p;
    const float nzs   = -(*zp_p) * scale;   // (q - zp)*s = q*s + (-zp*s)
    size_t i = (size_t)(blockIdx.x * (size_t)blockDim.x + threadIdx.x) * 8;
    i32x4v v0 = __builtin_nontemporal_load(reinterpret_cast<const i32x4v*>(q + i));
    i32x4v v1 = __builtin_nontemporal_load(reinterpret_cast<const i32x4v*>(q + i + 4));
    Pack8 p;
#pragma unroll
    for (int j = 0; j < 4; ++j) {
        p.h[j]     = to_bf16((float)v0[j] * scale + nzs);
        p.h[4 + j] = to_bf16((float)v1[j] * scale + nzs);
    }
    *reinterpret_cast<uint4*>(out + i) = p.u;
}

__device__ inline void async_load16(const void* gsrc, void* ldst) {
    __builtin_amdgcn_global_load_lds(
        (const __attribute__((address_space(1))) unsigned int*)gsrc,
        (__attribute__((address_space(3))) unsigned int*)ldst, 16, 0, 0);
}

// ---------------- fast path: 256x256x64 8-phase bf16 GEMM ----------------
// Schedule (per K-tile t, 4 phases; 2 K-tiles per "8-phase iter"):
//   phase q: ds_read A-quadrant q (rows q*64..q*64+63, XOR-swizzled)
//            [+ all 8 B frags in phase 0]
//            stage one half-tile:   p0: A-h1(t+1) | p1: B-h0(t+2) | p2: B-h1(t+2) | p3: A-h0(t+2)
//            s_barrier; lgkmcnt(0); setprio(1); 16 MFMA; setprio(0); s_barrier
//   boundary (after p3): s_waitcnt vmcnt(6)  -- 3 half-tiles (t+2's) stay in flight
// LDS swizzle (T2, both-sides): phys_byte = row*128 + (colbyte ^ ((row&7)<<4));
// global_load_lds writes linearly, so the SOURCE k-col is pre-swizzled.
// C epilogue: NON-TEMPORAL stores — the 360 MB C stream must not allocate in
// LLC (round-2 counters: FETCH=10x ideal from LLC thrash => supply-bound 7 TB/s).

constexpr int BM = 256, BN = 256, BK = 64;
constexpr int NT  = K_DIM / BK;            // 64 K-tiles
constexpr int NBN = N_DIM / BN;            // 43
constexpr int NWG = (M_DIM / BM) * NBN;    // 1376 (== 0 mod 8)

__global__ __launch_bounds__(512, 2)
void gemm_bf16_kernel(const __bf16* __restrict__ A, const __bf16* __restrict__ B,
                      const float* __restrict__ bias, float* __restrict__ C) {
    __shared__ __align__(16) __bf16 As[2][BM * BK];   // 2 x 32 KB
    __shared__ __align__(16) __bf16 Bs[2][BN * BK];   // 2 x 32 KB  (128 KB total)

    const int tid  = threadIdx.x;
    const int lane = tid & 63;
    const int wave = tid >> 6;       // 0..7
    const int wr   = wave >> 2;      // 0..1 (M)
    const int wc   = wave & 3;       // 0..3 (N)

    // T1: bijective XCD-contiguous remap (NWG % 8 == 0)
    int wg = (int)blockIdx.x;
    wg = (wg & 7) * (NWG >> 3) + (wg >> 3);
    const int bm = (wg / NBN) * BM;
    const int bn = (wg % NBN) * BN;

    // ---- staging geometry (inverse-swizzled global source, linear LDS dest) ----
    const int rc   = lane >> 3;                  // row within 8-row chunk
    const int scol = 8 * ((lane & 7) ^ rc);      // pre-swizzled k-col (bf16 elems)
    const int c0   = wave * 2;                   // this wave's 2 chunks per half-tile

#define STAGE_A(bufx, h, t) do {                                                      \
    _Pragma("unroll") for (int l = 0; l < 2; ++l) {                                   \
        const int c = c0 + l;                                                         \
        async_load16(A + (size_t)(bm + (h)*128 + c*8 + rc) * K_DIM + (t)*BK + scol,   \
                     (char*)As[bufx] + (h)*16384 + c*1024 + lane*16);                 \
    } } while (0)
#define STAGE_B(bufx, h, t) do {                                                      \
    _Pragma("unroll") for (int l = 0; l < 2; ++l) {                                   \
        const int c = c0 + l;                                                         \
        async_load16(B + (size_t)(bn + (h)*128 + c*8 + rc) * K_DIM + (t)*BK + scol,   \
                     (char*)Bs[bufx] + (h)*16384 + c*1024 + lane*16);                 \
    } } while (0)

    // ---- fragment-read geometry (swizzled ds_read_b128) ----
    const int lrow = lane & 15;
    const int swz  = (lane & 7) << 4;
    const int csw0 = (((lane >> 4) * 16)      ) ^ swz;   // ks=0 col-bytes, swizzled
    const int csw1 = (((lane >> 4) * 16) + 64 ) ^ swz;   // ks=1
    const int a_base = (wr * 32 + lrow) * 128;           // M interleaved at 32 rows
    const int b_base = (wc * 64 + lrow) * 128;

    f32x4 acc[8][4] = {};

    // ---- prologue: tile0 fully + tile1's first 3 half-tiles ----
    STAGE_B(0, 0, 0); STAGE_B(0, 1, 0); STAGE_A(0, 0, 0); STAGE_A(0, 1, 0);
    STAGE_B(1, 0, 1); STAGE_B(1, 1, 1); STAGE_A(1, 0, 1);
    asm volatile("s_waitcnt vmcnt(6)" ::: "memory");   // tile0 complete
    __builtin_amdgcn_s_barrier();

#define PHASE_Q(q, STAGE_STMT, TAIL) do {                                                         \
    bf16x8 a00 = *reinterpret_cast<const bf16x8*>(asp + a_base + (q)*8192 + csw0);                \
    bf16x8 a01 = *reinterpret_cast<const bf16x8*>(asp + a_base + (q)*8192 + csw1);                \
    bf16x8 a10 = *reinterpret_cast<const bf16x8*>(asp + a_base + (q)*8192 + 2048 + csw0);         \
    bf16x8 a11 = *reinterpret_cast<const bf16x8*>(asp + a_base + (q)*8192 + 2048 + csw1);         \
    STAGE_STMT;                                                                                   \
    __builtin_amdgcn_s_barrier();                                                                 \
    asm volatile("s_waitcnt lgkmcnt(0)" ::: "memory");                                            \
    __builtin_amdgcn_s_setprio(1);                                                                \
    _Pragma("unroll") for (int j = 0; j < 4; ++j) {                                               \
        acc[2*(q)  ][j] = __builtin_amdgcn_mfma_f32_16x16x32_bf16(a00, bfr[j][0], acc[2*(q)  ][j], 0,0,0); \
        acc[2*(q)  ][j] = __builtin_amdgcn_mfma_f32_16x16x32_bf16(a01, bfr[j][1], acc[2*(q)  ][j], 0,0,0); \
        acc[2*(q)+1][j] = __builtin_amdgcn_mfma_f32_16x16x32_bf16(a10, bfr[j][0], acc[2*(q)+1][j], 0,0,0); \
        acc[2*(q)+1][j] = __builtin_amdgcn_mfma_f32_16x16x32_bf16(a11, bfr[j][1], acc[2*(q)+1][j], 0,0,0); \
    }                                                                                             \
    __builtin_amdgcn_s_setprio(0);                                                                \
    TAIL;                                                                                         \
} while (0)

    for (int t = 0; t < NT; ++t) {
        const int buf = t & 1;
        const int nb  = buf ^ 1;
        const char* asp = (const char*)As[buf];
        const char* bsp = (const char*)Bs[buf];

        bf16x8 bfr[4][2];   // all B frags for this K-tile (read once, phase 0)
#pragma unroll
        for (int j = 0; j < 4; ++j) {
            bfr[j][0] = *reinterpret_cast<const bf16x8*>(bsp + b_base + j*2048 + csw0);
            bfr[j][1] = *reinterpret_cast<const bf16x8*>(bsp + b_base + j*2048 + csw1);
        }

        PHASE_Q(0, if (t + 1 < NT) STAGE_A(nb, 1, t + 1), __builtin_amdgcn_s_barrier());
        PHASE_Q(1, if (t + 2 < NT) STAGE_B(buf, 0, t + 2), __builtin_amdgcn_s_barrier());
        PHASE_Q(2, if (t + 2 < NT) STAGE_B(buf, 1, t + 2), __builtin_amdgcn_s_barrier());
        PHASE_Q(3, if (t + 2 < NT) STAGE_A(buf, 0, t + 2),
                { if (t < NT - 2)       { asm volatile("s_waitcnt vmcnt(6)" ::: "memory");
                                          __builtin_amdgcn_s_barrier(); }
                  else if (t == NT - 2) { asm volatile("s_waitcnt vmcnt(0)" ::: "memory");
                                          __builtin_amdgcn_s_barrier(); } });
    }

    // ---- epilogue: C/D layout col=lane&15, row=(lane>>4)*4+reg; NT stores ----
    const int col16 = lane & 15;
    const int rq    = (lane >> 4) * 4;
#pragma unroll
    for (int j = 0; j < 4; ++j) {
        const int n  = bn + wc * 64 + j * 16 + col16;
        const float bj = bias[n];
#pragma unroll
        for (int i = 0; i < 8; ++i) {
            const int row0 = bm + (i >> 1) * 64 + wr * 32 + (i & 1) * 16 + rq;
            size_t base = (size_t)row0 * N_DIM + n;
#pragma unroll
            for (int r = 0; r < 4; ++r)
                __builtin_nontemporal_store(acc[i][j][r] + bj, &C[base + (size_t)r * N_DIM]);
        }
    }
#undef PHASE_Q
#undef STAGE_A
#undef STAGE_B
}

// ---------------- fallback: fused dequant GEMM (no workspace needed) ----------------

constexpr int FBM = 128, FBN = 128, FBK = 64;

__device__ inline void mma_tile_f(const __bf16* As, const __bf16* Bs,
                                  f32x4 acc[4][4], int lane, int wm, int wn) {
    const int mrow = lane & 15;
#pragma unroll
    for (int ks = 0; ks < 2; ++ks) {
        const int kq = ks * 32 + (lane >> 4) * 8;
        bf16x8 a[4], b[4];
#pragma unroll
        for (int i = 0; i < 4; ++i) {
            a[i] = *reinterpret_cast<const bf16x8*>(As + (wm + i * 16 + mrow) * FBK + kq);
            b[i] = *reinterpret_cast<const bf16x8*>(Bs + (wn + i * 16 + mrow) * FBK + kq);
        }
#pragma unroll
        for (int i = 0; i < 4; ++i)
#pragma unroll
            for (int j = 0; j < 4; ++j)
                acc[i][j] = __builtin_amdgcn_mfma_f32_16x16x32_bf16(a[i], b[j], acc[i][j], 0, 0, 0);
    }
}

__global__ __launch_bounds__(256)
void gemm_fused_kernel(const float* __restrict__ A, const int* __restrict__ Q,
                       const float* __restrict__ scale_p, const float* __restrict__ zp_p,
                       const float* __restrict__ bias, float* __restrict__ C) {
    __shared__ __align__(16) __bf16 As[FBM * FBK];
    __shared__ __align__(16) __bf16 Bs[FBN * FBK];

    const float scale = *scale_p;
    const float nzs   = -(*zp_p) * scale;

    const int tid  = threadIdx.x;
    const int lane = tid & 63;
    const int wave = tid >> 6;
    const int bm = blockIdx.y * FBM;
    const int bn = blockIdx.x * FBN;
    const int wm = (wave >> 1) * 64;
    const int wn = (wave & 1) * 64;

    f32x4 acc[4][4] = {};

    for (int k0 = 0; k0 < K_DIM; k0 += FBK) {
        __syncthreads();
#pragma unroll
        for (int j = 0; j < 8; ++j) {
            const int e   = j * 1024 + tid * 4;
            const int row = e >> 6;
            const int col = e & 63;
            float4 v = *reinterpret_cast<const float4*>(A + (size_t)(bm + row) * K_DIM + k0 + col);
            Pack4 p;
            p.h[0] = to_bf16(v.x); p.h[1] = to_bf16(v.y);
            p.h[2] = to_bf16(v.z); p.h[3] = to_bf16(v.w);
            *reinterpret_cast<uint2*>(As + e) = p.u;

            int4 qv = *reinterpret_cast<const int4*>(Q + (size_t)(bn + row) * K_DIM + k0 + col);
            Pack4 pq;
            pq.h[0] = to_bf16((float)qv.x * scale + nzs);
            pq.h[1] = to_bf16((float)qv.y * scale + nzs);
            pq.h[2] = to_bf16((float)qv.z * scale + nzs);
            pq.h[3] = to_bf16((float)qv.w * scale + nzs);
            *reinterpret_cast<uint2*>(Bs + e) = pq.u;
        }
        __syncthreads();
        mma_tile_f(As, Bs, acc, lane, wm, wn);
    }

    const int col = lane & 15;
    const int rq  = (lane >> 4) * 4;
#pragma unroll
    for (int j = 0; j < 4; ++j) {
        const int n  = bn + wn + j * 16 + col;
        const float bj = bias[n];
#pragma unroll
        for (int i = 0; i < 4; ++i) {
            size_t base = (size_t)(bm + wm + i * 16 + rq) * N_DIM + n;
#pragma unroll
            for (int r = 0; r < 4; ++r)
                C[base + (size_t)r * N_DIM] = acc[i][j][r] + bj;
        }
    }
}

// ---------------- launch ----------------

extern "C" void kernel_launch(void* const* d_in, const int* in_sizes, int n_in,
                              void* d_out, int out_size, void* d_ws, size_t ws_size,
                              hipStream_t stream) {
    const float* x     = (const float*)d_in[0];
    const int*   qw    = (const int*)d_in[1];
    const float* scale = (const float*)d_in[2];
    const float* zp    = (const float*)d_in[3];
    const float* bias  = (const float*)d_in[4];
    float* out = (float*)d_out;

    const size_t needA = (size_t)M_DIM * K_DIM * sizeof(__bf16);   // 67.1 MB
    const size_t needB = (size_t)N_DIM * K_DIM * sizeof(__bf16);   // 90.2 MB

    if (ws_size >= needA + needB) {
        __bf16* Abf = (__bf16*)d_ws;
        __bf16* Bbf = (__bf16*)((char*)d_ws + needA);
        cvt_x_kernel<<<(M_DIM * (size_t)K_DIM / 8) / 256, 256, 0, stream>>>(x, Abf);
        cvt_w_kernel<<<(N_DIM * (size_t)K_DIM / 8) / 256, 256, 0, stream>>>(qw, scale, zp, Bbf);
        gemm_bf16_kernel<<<dim3(NWG), 512, 0, stream>>>(Abf, Bbf, bias, out);
    } else {
        gemm_fused_kernel<<<dim3(N_DIM / FBN, M_DIM / FBM), 256, 0, stream>>>(x, qw, scale, zp, bias, out);
    }
}